// Round 10
// baseline (2863.790 us; speedup 1.0000x reference)
//
#include <hip/hip_runtime.h>

// Decoder_8014408974552 R14: 4-role shared-row blocks -> 2 waves/SIMD in the
// SAFE register regime. R13 failed because LDS-resident h + in-place blend
// corrupts old h (all-to-all K dependency). R14 keeps R4's correctness model
// (gh A-ops from hold[] regs; in-place blend; reload after barrier) and
// changes the PARALLELIZATION: block = 32 rows x 4 waves; wave w = role w
// owns chunks 3w..3w+2. Effects: (1) B-frag LDS reads per wave /4 (no 4x
// redundant reads of identical weights); (2) LDS/block = 74752 B -> 2
// blocks/CU -> 8 waves/CU = 2 waves/SIMD with INDEPENDENT barriers (one
// block's stage-drain hides under the other's compute); (3) 256-thr blocks
// -> empirically-proven >=244 VGPR budget; launch_bounds(256,2) caps 256
// under both candidate semantics. 1024 blocks; 75 phases/t x 16KB (4 frags
// per role per phase). Per-gate accumulation order identical to R4.

#define TT   30
#define NPH  75     // phases per timestep
#define SPU  8192   // u16 per phase (16 KB = 4 roles x 4 frags x 1KB)
#define HS   392    // hn row stride in u16 (784 B; cols 384..391 = sst)
#define XFO(kf,hh,mm) (((kf)*2+(hh))*264 + (mm)*8)

typedef unsigned short u16;
typedef __bf16 bf16x8 __attribute__((ext_vector_type(8)));
typedef u16    u16x8  __attribute__((ext_vector_type(8)));
typedef float  f32x16 __attribute__((ext_vector_type(16)));

__device__ __forceinline__ u16 f2b(float f){           // fp32 -> bf16 RNE
  unsigned u = __float_as_uint(f);
  u += 0x7FFFu + ((u >> 16) & 1u);
  return (u16)(u >> 16);
}
__device__ __forceinline__ float b2f(u16 h){ return __uint_as_float(((unsigned)h) << 16); }

__device__ __forceinline__ f32x16 mfma32(u16x8 a, u16x8 b, f32x16 c){
  return __builtin_amdgcn_mfma_f32_32x32x16_bf16(
      __builtin_bit_cast(bf16x8, a), __builtin_bit_cast(bf16x8, b), c, 0, 0, 0);
}
__device__ __forceinline__ void lds_fence(){ asm volatile("s_waitcnt lgkmcnt(0)" ::: "memory"); }
__device__ __forceinline__ void vm_fence(){ asm volatile("s_waitcnt vmcnt(0)" ::: "memory"); }
__device__ __forceinline__ float sigf(float x){ return __builtin_amdgcn_rcpf(1.f + __expf(-x)); }
__device__ __forceinline__ float tanh_(float x){ return 2.f*__builtin_amdgcn_rcpf(1.f + __expf(-2.f*x)) - 1.f; }

__device__ __forceinline__ void stage16(const u16* g, u16* l){
  __builtin_amdgcn_global_load_lds(
      (const __attribute__((address_space(1))) unsigned int*)g,
      (__attribute__((address_space(3))) unsigned int*)l, 16, 0, 0);
}

// ---------------------------------------------------------------- prep ----
// Role r (0..3) owns chunks 3r..3r+2. Per-role frag sequence q (300 frags):
//   chunk ci (0..2): gi  q = ci*96 + g*8 + kf     (g=0..2, kf=0..7)
//                    gh  q = ci*96 + 24 + g*24+kf (g=0..2, kf=0..23)
//   decode: role r covers Wd1 tile (r>>1), K-half (r&1): q = 288 + kf'
// phase sp=q/4, slot f=q%4; u16 offset =
//   sp*SPU + r*2048 + f*512 + (lc+32*hl)*8 + j
__global__ void prep_kernel(const float* __restrict__ Wih, const float* __restrict__ Whh,
                            const float* __restrict__ Wd1, const float* __restrict__ Wd2,
                            const float* __restrict__ bih, const float* __restrict__ bhh,
                            const float* __restrict__ Ws,  const float* __restrict__ bs,
                            const float* __restrict__ Wp,  const float* __restrict__ bp,
                            u16* __restrict__ stream, u16* __restrict__ wd2p,
                            u16* __restrict__ wxp, float* __restrict__ gb)
{
  int i = blockIdx.x*blockDim.x + threadIdx.x;
  if (i < 442368){  // W_hh [1152][384]
    int row = i/384, k = i - row*384;
    int g = row/384, unit = row - g*384, c = unit>>5, lc = unit&31;
    int kf = k>>4, hl = (k>>3)&1, j = k&7;
    int role = c/3, ci = c - role*3;
    int q = ci*96 + 24 + g*24 + kf;
    int sp = q>>2, f = q&3;
    stream[(size_t)sp*SPU + role*2048 + f*512 + (lc+32*hl)*8 + j] = f2b(Whh[i]);
  }
  if (i < 147456){  // W_ih [1152][128]
    int row = i>>7, k = i&127;
    int g = row/384, unit = row - g*384, c = unit>>5, lc = unit&31;
    int kf = k>>4, hl = (k>>3)&1, j = k&7;
    int role = c/3, ci = c - role*3;
    int q = ci*96 + g*8 + kf;
    int sp = q>>2, f = q&3;
    stream[(size_t)sp*SPU + role*2048 + f*512 + (lc+32*hl)*8 + j] = f2b(Wih[i]);
  }
  if (i < 24576){   // Wd1 [64][384]
    int row = i/384, k = i - row*384;
    int tl = row>>5, lc = row&31;
    int kf = k>>4, hl = (k>>3)&1, j = k&7;
    int kh = kf/12, kfp = kf - kh*12;
    int role = tl*2 + kh;
    int q = 288 + kfp;
    int sp = q>>2, f = q&3;
    stream[(size_t)sp*SPU + role*2048 + f*512 + (lc+32*hl)*8 + j] = f2b(Wd1[i]);
  }
  if (i < 2048){    // Wd2 padded B-frags [4 kf][512] (n>=3 -> 0)
    int kf = i>>9, r = i&511;
    int n = (r>>3)&31, hl = r>>8, j = r&7;
    int k = kf*16 + hl*8 + j;
    wd2p[i] = f2b((n<3) ? Wd2[n*64 + k] : 0.f);
  }
  if (i < 2048){    // x-MLP B-frags [4 tiles][512]: K=16 (k=0..7 feat, 8..15 zero)
    int tl = i>>9, r = i&511;
    int n = (r>>3)&31, hl = r>>8, j = r&7;
    int k = hl*8 + j, u = tl*32 + n;
    float v = 0.f;
    if      (k <= 2) v = Ws[u*3 + k];
    else if (k == 3) v = bs[u];
    else if (k <= 6) v = Wp[u*3 + (k-4)];
    else if (k == 7) v = bp[u];
    wxp[i] = f2b(v);
  }
  if (i < 384){     // fused gate biases per hidden unit: {r, z, n_i, n_h}
    gb[i*4+0] = bih[i]       + bhh[i];
    gb[i*4+1] = bih[384+i]   + bhh[384+i];
    gb[i*4+2] = bih[768+i];
    gb[i*4+3] = bhh[768+i];
  }
}

// ---------------------------------------------------------------- main ----
__global__ __launch_bounds__(256, 2)
void gru_main(const float* __restrict__ ih, const float* __restrict__ plan,
              const float* __restrict__ gate, const float* __restrict__ istate,
              const u16* __restrict__ stream, const u16* __restrict__ wd2p,
              const u16* __restrict__ wxp, const float* __restrict__ gb,
              const float* __restrict__ bd1, const float* __restrict__ bd2,
              float* __restrict__ out)
{
  __shared__ __attribute__((aligned(16))) u16 wb[2][SPU];   // 32768 B
  __shared__ __attribute__((aligned(16))) u16 hn[32*HS];    // 25088 B (shared h + sst pad)
  __shared__ __attribute__((aligned(16))) u16 xsc[16*264];  //  8448 B (x / elu A-frags)
  __shared__ float scr[2][32*33];                           //  8448 B (d1 reduction)
  // total 74752 B <= 81920 -> 2 blocks/CU = 8 waves/CU = 2 waves/SIMD

  const int tid  = threadIdx.x;
  const int wave = tid >> 6, lane = tid & 63;     // wave = role 0..3
  const int m    = lane & 31, hl = lane >> 5;
  const int R0   = blockIdx.x*32;                 // block's 32 batch rows

  const float gt   = gate[R0 + m];
  const float bd1v = (wave&1) ? 0.f : bd1[(wave>>1)*32 + m];
  const float bd2v = (m<3) ? bd2[m] : 0.f;

  if (wave==0 && lane < 32){    // sst in hn pad (cols 384..391 = 4 f32)
    const float* sp = istate + (size_t)(R0+lane)*3;
    float* q = (float*)&hn[lane*HS + 384];
    q[0]=sp[0]; q[1]=sp[1]; q[2]=sp[2]; q[3]=0.f;
  }

  // initial hidden -> hold regs (all waves, same rows) + LDS hn (wave 0)
  u16x8 hold[24];
#pragma unroll
  for (int kf=0; kf<24; ++kf){
    const float* p = ih + (size_t)(R0+m)*384 + kf*16 + hl*8;
    float4 a = *(const float4*)p;
    float4 b = *(const float4*)(p+4);
    u16x8 v;
    v[0]=f2b(a.x); v[1]=f2b(a.y); v[2]=f2b(a.z); v[3]=f2b(a.w);
    v[4]=f2b(b.x); v[5]=f2b(b.y); v[6]=f2b(b.z); v[7]=f2b(b.w);
    hold[kf]=v;
    if (wave==0) *(u16x8*)&hn[m*HS + kf*16 + hl*8] = v;
  }

  const u16* srcb = stream + wave*2048 + lane*8;
  auto stage = [&](int sp, int bsel){   // 16KB phase: each wave stages its 4KB quarter
    const u16* s = srcb + (size_t)sp*SPU;
    u16* d = &wb[bsel][wave*2048];
#pragma unroll
    for (int ii=0; ii<4; ++ii) stage16(s + ii*512, d + ii*512);
  };

  stage(0, 0);
  vm_fence(); __syncthreads();
  int buf = 0, gp = 0;

#pragma unroll 1
  for (int t=0; t<TT; ++t){
    // ---- x-phase: each role computes tile 'wave' of x, writes A-frags to xsc
    u16x8 a8;
    {
      float4 sv = *(const float4*)&hn[m*HS + 384];
      const float* pp = plan + (size_t)(R0+m)*(TT*3) + t*3;
      float f0=sv.x, f1=sv.y, f2=sv.z, f3=1.f;
      float f4=gt*pp[0], f5=gt*pp[1], f6=gt*pp[2], f7=gt;
      if (hl){ a8[0]=0;a8[1]=0;a8[2]=0;a8[3]=0;a8[4]=0;a8[5]=0;a8[6]=0;a8[7]=0; }
      else { a8[0]=f2b(f0);a8[1]=f2b(f1);a8[2]=f2b(f2);a8[3]=f2b(f3);
             a8[4]=f2b(f4);a8[5]=f2b(f5);a8[6]=f2b(f6);a8[7]=f2b(f7); }
    }
    {
      f32x16 ax;
#pragma unroll
      for (int r=0;r<16;++r) ax[r]=0.f;
      ax = mfma32(a8, *(const u16x8*)(wxp + wave*512 + lane*8), ax);
#pragma unroll
      for (int r=0;r<16;++r){
        int row = (r&3) + ((r>>2)<<3) + 4*hl;
        int kfx = 2*wave + (m>>4);
        xsc[(kfx*2 + ((m>>3)&1))*264 + row*8 + (m&7)] = f2b(ax[r]);
      }
    }
    __syncthreads();
    u16x8 xf[8];
#pragma unroll
    for (int kf=0; kf<8; ++kf) xf[kf] = *(const u16x8*)&xsc[XFO(kf,hl,m)];
    lds_fence();

    // ---- role's 3 chunks x (6 gi + 18 gh) phases
#pragma unroll 1
    for (int ci=0; ci<3; ++ci){
      const int c = 3*wave + ci;          // h columns c*32..c*32+31
      f32x16 aR, aZ, aNI, aNH;
      {
        const float4 b4 = *(const float4*)(gb + (size_t)(c*32+m)*4);
#pragma unroll
        for (int r=0;r<16;++r){ aR[r]=b4.x; aZ[r]=b4.y; aNI[r]=b4.z; aNH[r]=b4.w; }
      }
#pragma unroll
      for (int pg=0; pg<6; ++pg){         // gi: idx = g*8+kf
        int np = gp+1; stage(np, buf^1);
        const u16* W = wb[buf] + wave*2048;
#pragma unroll
        for (int s=0; s<4; ++s){
          int idx = pg*4+s, g = idx>>3, kf = idx&7;
          u16x8 B = *(const u16x8*)(W + s*512 + lane*8);
          if      (g==0) aR  = mfma32(xf[kf], B, aR);
          else if (g==1) aZ  = mfma32(xf[kf], B, aZ);
          else           aNI = mfma32(xf[kf], B, aNI);
        }
        vm_fence(); __syncthreads(); buf^=1; gp=np;
      }
#pragma unroll
      for (int pp=0; pp<18; ++pp){        // gh: idx = g*24+kf
        int np = gp+1; stage(np, buf^1);
        const u16* W = wb[buf] + wave*2048;
#pragma unroll
        for (int s=0; s<4; ++s){
          int idx = pp*4+s, g = idx/24, kf = idx - g*24;
          u16x8 B = *(const u16x8*)(W + s*512 + lane*8);
          if      (g==0) aR  = mfma32(hold[kf], B, aR);
          else if (g==1) aZ  = mfma32(hold[kf], B, aZ);
          else           aNH = mfma32(hold[kf], B, aNH);
        }
        if (pp==17){   // GRU blend, in place (role-disjoint columns)
#pragma unroll
          for (int r=0;r<16;++r){
            int row = (r&3) + ((r>>2)<<3) + 4*hl;
            float rr = sigf(aR[r]);
            float zz = sigf(aZ[r]);
            float nn = tanh_(aNI[r] + rr*aNH[r]);
            int off = row*HS + c*32 + m;
            float ho = b2f(hn[off]);             // old h
            hn[off] = f2b((1.f-zz)*nn + zz*ho);  // new h
          }
        }
        vm_fence(); __syncthreads(); buf^=1; gp=np;
      }
    } // chunks

    // ---- reload hold[] (all blends barrier-ordered before this)
#pragma unroll
    for (int kf=0; kf<24; ++kf)
      hold[kf] = *(const u16x8*)&hn[m*HS + kf*16 + hl*8];

    // ---- decode: role's Wd1 portion (tile wave>>1, K-half wave&1), 3 phases
    f32x16 a0;
#pragma unroll
    for (int r=0;r<16;++r) a0[r]=bd1v;
#pragma unroll
    for (int pd=0; pd<3; ++pd){
      int np = (gp+1 == NPH) ? 0 : gp+1;
      stage(np, buf^1);
      const u16* W = wb[buf] + wave*2048;
      if (wave & 1){
#pragma unroll
        for (int s=0; s<4; ++s)
          a0 = mfma32(hold[12 + pd*4+s], *(const u16x8*)(W + s*512 + lane*8), a0);
      } else {
#pragma unroll
        for (int s=0; s<4; ++s)
          a0 = mfma32(hold[pd*4+s], *(const u16x8*)(W + s*512 + lane*8), a0);
      }
      vm_fence(); __syncthreads(); buf^=1; gp=np;
    }
    // ---- cross-role d1 reduction + elu + d2 + out
    if (wave & 1){                         // roles 1,3: hand partial to owner
      float* sp_ = scr[wave>>1];
#pragma unroll
      for (int r=0;r<16;++r){
        int row = (r&3) + ((r>>2)<<3) + 4*hl;
        sp_[row*33 + m] = a0[r];
      }
    }
    __syncthreads();
    if (!(wave & 1)){                      // roles 0,2: sum, elu, A-frags
      const float* sp_ = scr[wave>>1];
      const int kb = (wave==0) ? 0 : 2;
#pragma unroll
      for (int r=0;r<16;++r){
        int row = (r&3) + ((r>>2)<<3) + 4*hl;
        float e = a0[r] + sp_[row*33 + m];
        e = e>0.f ? e : (__expf(e)-1.f);
        int kfd = kb + (m>>4);
        xsc[(kfd*2 + ((m>>3)&1))*264 + row*8 + (m&7)] = f2b(e);
      }
    }
    __syncthreads();
    if (wave==0){                          // d2 + out + state update
      u16x8 wd2f0 = *(const u16x8*)(wd2p + 0*512 + lane*8);
      u16x8 wd2f1 = *(const u16x8*)(wd2p + 1*512 + lane*8);
      u16x8 wd2f2 = *(const u16x8*)(wd2p + 2*512 + lane*8);
      u16x8 wd2f3 = *(const u16x8*)(wd2p + 3*512 + lane*8);
      u16x8 af0 = *(const u16x8*)&xsc[XFO(0,hl,m)];
      u16x8 af1 = *(const u16x8*)&xsc[XFO(1,hl,m)];
      u16x8 af2 = *(const u16x8*)&xsc[XFO(2,hl,m)];
      u16x8 af3 = *(const u16x8*)&xsc[XFO(3,hl,m)];
      f32x16 ao;
#pragma unroll
      for (int r=0;r<16;++r) ao[r]=0.f;
      ao = mfma32(af0, wd2f0, ao);
      ao = mfma32(af1, wd2f1, ao);
      ao = mfma32(af2, wd2f2, ao);
      ao = mfma32(af3, wd2f3, ao);
#pragma unroll
      for (int r=0;r<16;++r){
        int row = (r&3) + ((r>>2)<<3) + 4*hl;
        if (m < 3){
          float* q = (float*)&hn[row*HS + 384];
          float ns = q[m] + ao[r] + bd2v;
          out[(size_t)(R0+row)*(TT*3) + t*3 + m] = ns;
          q[m] = ns;
        }
      }
    }
    __syncthreads();   // sst/xsc safe before next t's x-phase
  } // t
}

// -------------------------------------------------------------- launch ----
extern "C" void kernel_launch(void* const* d_in, const int* in_sizes, int n_in,
                              void* d_out, int out_size, void* d_ws, size_t ws_size,
                              hipStream_t stream)
{
  (void)in_sizes; (void)n_in; (void)out_size; (void)ws_size;
  const float* ih     = (const float*)d_in[0];
  const float* plan   = (const float*)d_in[1];
  const float* gatep  = (const float*)d_in[2];
  const float* istate = (const float*)d_in[3];
  const float* Wp     = (const float*)d_in[4];
  const float* bp     = (const float*)d_in[5];
  const float* Ws     = (const float*)d_in[6];
  const float* bs     = (const float*)d_in[7];
  const float* Wih    = (const float*)d_in[8];
  const float* bih    = (const float*)d_in[9];
  const float* Whh    = (const float*)d_in[10];
  const float* bhh    = (const float*)d_in[11];
  const float* Wd1    = (const float*)d_in[12];
  const float* bd1    = (const float*)d_in[13];
  const float* Wd2    = (const float*)d_in[14];
  const float* bd2    = (const float*)d_in[15];

  // workspace layout (~1.25 MB)
  u16*   wstream = (u16*)d_ws;                         // 614400 u16 = 1228800 B
  u16*   wd2p    = (u16*)((char*)d_ws + 1228800);      //   2048 u16 =    4096 B
  u16*   wxp     = (u16*)((char*)d_ws + 1232896);      //   2048 u16 =    4096 B
  float* gb      = (float*)((char*)d_ws + 1236992);    //   1536 f32 =    6144 B

  prep_kernel<<<1728, 256, 0, stream>>>(Wih, Whh, Wd1, Wd2, bih, bhh, Ws, bs, Wp, bp,
                                        wstream, wd2p, wxp, gb);
  gru_main<<<1024, 256, 0, stream>>>(ih, plan, gatep, istate,
                                     wstream, wd2p, wxp, gb, bd1, bd2, (float*)d_out);
}

// Round 11
// 1598.197 us; speedup vs baseline: 1.7919x; 1.7919x over previous
//
#include <hip/hip_runtime.h>

// Decoder_8014408974552 R15: R11 + full-phase B-frag register preload.
// R14 POST-MORTEM: every 8-waves/CU config caps arch VGPR at 128 (3rd
// confirmation) -> 2-waves/SIMD is unreachable with hold[96]. And it's
// unnecessary: m119 peak => 32x32x16 MFMA occupies ~32cyc/SIMD, so ONE wave
// can saturate the matrix pipe. The ~70% idle is within-phase ds_read->MFMA
// latency at shallow prefetch depth: compiler sized us 212-244 VGPR, but at
// 1 wave/SIMD (LDS-forced: 161KB -> 1 block/CU) the cap is 512 -- ~270 regs
// sat unused. R15 spends them: each phase loads all 24 B-frags into bf[24]
// (96 VGPRs, constant indices after unroll) before the MFMA chain -> 24
// ds_reads issue back-to-back, MFMAs run at pipe depth, lgkm stalls collapse.
// Operand values and accumulation order identical to R11 -> same numerics.
// Everything else (5-slot counted-vmcnt staging, phase_end, sst-in-hn pad,
// prep/stream layout) = R11 verbatim.

#define TT  30
#define NPH 50
#define PHU 12288   // u16 per phase (24576 B) -- prep layout unit
#define HPU 6144    // u16 per half-phase slot (12288 B)
#define STRU 614400 // u16 in the whole stream (100 halves)
#define HS  392     // hn row stride in u16 (784 B; cols 384..391 = sst)

typedef unsigned short u16;
typedef __bf16 bf16x8 __attribute__((ext_vector_type(8)));
typedef u16    u16x8  __attribute__((ext_vector_type(8)));
typedef float  f32x16 __attribute__((ext_vector_type(16)));

__device__ __forceinline__ u16 f2b(float f){           // fp32 -> bf16 RNE
  unsigned u = __float_as_uint(f);
  u += 0x7FFFu + ((u >> 16) & 1u);
  return (u16)(u >> 16);
}
__device__ __forceinline__ float b2f(u16 h){ return __uint_as_float(((unsigned)h) << 16); }

__device__ __forceinline__ f32x16 mfma32(u16x8 a, u16x8 b, f32x16 c){
  return __builtin_amdgcn_mfma_f32_32x32x16_bf16(
      __builtin_bit_cast(bf16x8, a), __builtin_bit_cast(bf16x8, b), c, 0, 0, 0);
}
__device__ __forceinline__ void lds_fence(){
  asm volatile("s_waitcnt lgkmcnt(0)" ::: "memory");
  __builtin_amdgcn_sched_barrier(0);
}
__device__ __forceinline__ float sigf(float x){ return __builtin_amdgcn_rcpf(1.f + __expf(-x)); }
__device__ __forceinline__ float tanh_(float x){ return 2.f*__builtin_amdgcn_rcpf(1.f + __expf(-2.f*x)) - 1.f; }

__device__ __forceinline__ void stage16(const u16* g, u16* l){
  __builtin_amdgcn_global_load_lds(
      (const __attribute__((address_space(1))) unsigned int*)g,
      (__attribute__((address_space(3))) unsigned int*)l, 16, 0, 0);
}

// ---------------------------------------------------------------- prep ----
// EXACT R4/R11 layout (50 phases x 24 frags x 1024 B per step):
//   c*4+0 : gi  [gi_r kf0..7][gi_z kf0..7][gi_n kf0..7]   (K=128)
//   c*4+1 : gh_r kf0..23   c*4+2 : gh_z   c*4+3 : gh_n     (K=384)
//   48,49 : Wd1 col-tile 0,1  kf0..23
// frag: u16 idx (lane&31 + 32*(lane>>5))*8 + j -> B[k][n], n=c*32+(lane&31),
// k = kf*16 + (lane>>5)*8 + j.  (Half-phase h = 2p + f/12 at h*HPU.)
__global__ void prep_kernel(const float* __restrict__ Wih, const float* __restrict__ Whh,
                            const float* __restrict__ Wd1, const float* __restrict__ Wd2,
                            const float* __restrict__ bih, const float* __restrict__ bhh,
                            const float* __restrict__ Ws,  const float* __restrict__ bs,
                            const float* __restrict__ Wp,  const float* __restrict__ bp,
                            u16* __restrict__ stream, u16* __restrict__ wd2p,
                            u16* __restrict__ wxp, float* __restrict__ gb)
{
  int i = blockIdx.x*blockDim.x + threadIdx.x;
  if (i < 442368){  // W_hh [1152][384]
    int row = i/384, k = i - row*384;
    int g = row/384, unit = row - g*384, c = unit>>5, lc = unit&31;
    int kf = k>>4, hl = (k>>3)&1, j = k&7;
    int phase = c*4 + 1 + g;
    stream[(size_t)phase*PHU + kf*512 + (lc+32*hl)*8 + j] = f2b(Whh[i]);
  }
  if (i < 147456){  // W_ih [1152][128]
    int row = i>>7, k = i&127;
    int g = row/384, unit = row - g*384, c = unit>>5, lc = unit&31;
    int kf = k>>4, hl = (k>>3)&1, j = k&7;
    int phase = c*4;
    stream[(size_t)phase*PHU + (g*8+kf)*512 + (lc+32*hl)*8 + j] = f2b(Wih[i]);
  }
  if (i < 24576){   // Wd1 [64][384]
    int row = i/384, k = i - row*384;
    int ct = row>>5, lc = row&31;
    int kf = k>>4, hl = (k>>3)&1, j = k&7;
    int phase = 48 + ct;
    stream[(size_t)phase*PHU + kf*512 + (lc+32*hl)*8 + j] = f2b(Wd1[i]);
  }
  if (i < 2048){    // Wd2 padded B-frags [4 kf][512] (n>=3 -> 0)
    int kf = i>>9, r = i&511;
    int n = (r>>3)&31, hl = r>>8, j = r&7;
    int k = kf*16 + hl*8 + j;
    wd2p[i] = f2b((n<3) ? Wd2[n*64 + k] : 0.f);
  }
  if (i < 2048){    // x-MLP B-frags [4 tiles][512]: K=16 (k=0..7 feat, 8..15 zero)
    int tl = i>>9, r = i&511;
    int n = (r>>3)&31, hl = r>>8, j = r&7;
    int k = hl*8 + j, u = tl*32 + n;
    float v = 0.f;
    if      (k <= 2) v = Ws[u*3 + k];
    else if (k == 3) v = bs[u];
    else if (k <= 6) v = Wp[u*3 + (k-4)];
    else if (k == 7) v = bp[u];
    wxp[i] = f2b(v);
  }
  if (i < 384){     // fused gate biases per hidden unit: {r, z, n_i, n_h}
    gb[i*4+0] = bih[i]       + bhh[i];
    gb[i*4+1] = bih[384+i]   + bhh[384+i];
    gb[i*4+2] = bih[768+i];
    gb[i*4+3] = bhh[768+i];
  }
}

// ---------------------------------------------------------------- main ----
__global__ __launch_bounds__(256, 1)
void gru_main(const float* __restrict__ ih, const float* __restrict__ plan,
              const float* __restrict__ gate, const float* __restrict__ istate,
              const u16* __restrict__ stream, const u16* __restrict__ wd2p,
              const u16* __restrict__ wxp, const float* __restrict__ gb,
              const float* __restrict__ bd1, const float* __restrict__ bd2,
              float* __restrict__ out)
{
  __shared__ __attribute__((aligned(16))) u16 wb[5*HPU];    //  61440 B, 5 half-slots
  __shared__ __attribute__((aligned(16))) u16 hn[4][32*HS]; // 100352 B (h + sst pad)
  // total 161792 B <= 163840 -> 1 block/CU (LDS-bound), 1 wave/SIMD, VGPR cap 512

  const int tid  = threadIdx.x;
  const int wave = tid >> 6, lane = tid & 63;
  const int m    = lane & 31, hl = lane >> 5;
  const int R0   = blockIdx.x*128 + wave*32;   // wave's 32 batch rows
  u16* hw = hn[wave];

  const float gt    = gate[R0 + m];
  const float bd1v0 = bd1[m], bd1v1 = bd1[32+m];
  const float bd2v  = (m<3) ? bd2[m] : 0.f;

  if (lane < 32){   // sst lives in hn row padding (cols 384..391 = 4 f32)
    const float* sp = istate + (size_t)(R0+lane)*3;
    float* q = (float*)&hw[lane*HS + 384];
    q[0]=sp[0]; q[1]=sp[1]; q[2]=sp[2]; q[3]=0.f;
  }

  // initial hidden -> A-frags AND the persistent LDS h-buffer
  u16x8 hold[24];
#pragma unroll
  for (int kf=0; kf<24; ++kf){
    const float* p = ih + (size_t)(R0+m)*384 + kf*16 + hl*8;
    float4 a = *(const float4*)p;
    float4 b = *(const float4*)(p+4);
    u16x8 v;
    v[0]=f2b(a.x); v[1]=f2b(a.y); v[2]=f2b(a.z); v[3]=f2b(a.w);
    v[4]=f2b(b.x); v[5]=f2b(b.y); v[6]=f2b(b.z); v[7]=f2b(b.w);
    hold[kf]=v;
    *(u16x8*)&hw[m*HS + kf*16 + hl*8] = v;
  }

  // ---- counted-vmcnt staging pipeline state (R11) ----
  int hoff = 0;            // stream u16 offset of next half to stage (wraps)
  int ss   = 0;            // its slot (= half index mod 5)
  int sa   = 0, sb = 1;    // slots read by the current phase
  auto stage_half = [&](){ // one 12KB half: 3 stage16 per wave
    const u16* s = stream + hoff + wave*1536 + lane*8;
    u16* d = &wb[ss*HPU + wave*1536];
    stage16(s,        d);
    stage16(s + 512,  d + 512);
    stage16(s + 1024, d + 1024);
    hoff += HPU; if (hoff == STRU) hoff = 0;
    ss = (ss==4) ? 0 : ss+1;
  };
  auto phase_end = [&](){  // counted wait: leave the newest half in flight
    asm volatile("s_waitcnt vmcnt(3) lgkmcnt(0)" ::: "memory");
    __builtin_amdgcn_sched_barrier(0);
    __builtin_amdgcn_s_barrier();
    __builtin_amdgcn_sched_barrier(0);
    sa = (sa>=3) ? sa-3 : sa+2;
    sb = (sb>=3) ? sb-3 : sb+2;
  };
  // preload all 24 B-frags of the current phase into registers
  auto preload = [&](u16x8* bf){
    const u16* W0 = wb + sa*HPU + lane*8;
    const u16* W1 = wb + sb*HPU + lane*8;
#pragma unroll
    for (int f=0; f<12; ++f) bf[f]      = *(const u16x8*)(W0 + f*512);
#pragma unroll
    for (int f=0; f<12; ++f) bf[12+f]   = *(const u16x8*)(W1 + f*512);
  };

  // prologue: halves 0,1 landed; half 2 in flight
  stage_half(); stage_half(); stage_half();
  asm volatile("s_waitcnt vmcnt(3) lgkmcnt(0)" ::: "memory");
  __builtin_amdgcn_sched_barrier(0);
  __builtin_amdgcn_s_barrier();
  __builtin_amdgcn_sched_barrier(0);

#pragma unroll 1
  for (int t=0; t<TT; ++t){
    // ---- x = (state@Ws^T+bs) + gate*(plan@Wp^T+bp) via one padded-K MFMA per tile
    u16x8 a8;
    {
      float4 sv = *(const float4*)&hw[m*HS + 384];   // sst in hn padding
      const float* pp = plan + (size_t)(R0+m)*(TT*3) + t*3;
      float f0=sv.x, f1=sv.y, f2=sv.z, f3=1.f;
      float f4=gt*pp[0], f5=gt*pp[1], f6=gt*pp[2], f7=gt;
      if (hl){ a8[0]=0;a8[1]=0;a8[2]=0;a8[3]=0;a8[4]=0;a8[5]=0;a8[6]=0;a8[7]=0; }
      else { a8[0]=f2b(f0);a8[1]=f2b(f1);a8[2]=f2b(f2);a8[3]=f2b(f3);
             a8[4]=f2b(f4);a8[5]=f2b(f5);a8[6]=f2b(f6);a8[7]=f2b(f7); }
    }
    u16x8 xf[8];
#pragma unroll
    for (int tl=0; tl<4; ++tl){
      f32x16 ax;
#pragma unroll
      for (int r=0;r<16;++r) ax[r]=0.f;
      ax = mfma32(a8, *(const u16x8*)(wxp + tl*512 + lane*8), ax);
      // C-layout -> hn chunk-0 slice (scratch) -> A-frags
#pragma unroll
      for (int r=0;r<16;++r){
        int row = (r&3) + ((r>>2)<<3) + 4*hl;
        hw[row*HS + m] = f2b(ax[r]);
      }
      lds_fence();
      xf[2*tl]   = *(const u16x8*)&hw[m*HS + hl*8];
      xf[2*tl+1] = *(const u16x8*)&hw[m*HS + 16 + hl*8];
      lds_fence();
    }
    // restore chunk-0 slice of old h from hold (CONSTANT indices)
    *(u16x8*)&hw[m*HS + hl*8]      = hold[0];
    *(u16x8*)&hw[m*HS + 16 + hl*8] = hold[1];
    lds_fence();

#pragma unroll 1
    for (int c=0; c<12; ++c){
      f32x16 aR, aZ, aNI, aNH;
      {
        const float4 b4 = *(const float4*)(gb + (size_t)(c*32+m)*4);
#pragma unroll
        for (int r=0;r<16;++r){ aR[r]=b4.x; aZ[r]=b4.y; aNI[r]=b4.z; aNH[r]=b4.w; }
      }
      { // phase c*4: gi -- preload 24 frags, then 3x8 MFMAs
        stage_half(); stage_half();
        u16x8 bf[24]; preload(bf);
#pragma unroll
        for (int kf=0; kf<8; ++kf){
          aR  = mfma32(xf[kf], bf[kf],    aR);
          aZ  = mfma32(xf[kf], bf[8+kf],  aZ);
          aNI = mfma32(xf[kf], bf[16+kf], aNI);
        }
        phase_end();
      }
      { // phase c*4+1: gh_r
        stage_half(); stage_half();
        u16x8 bf[24]; preload(bf);
#pragma unroll
        for (int kf=0; kf<24; ++kf)
          aR = mfma32(hold[kf], bf[kf], aR);
        phase_end();
      }
      { // phase c*4+2: gh_z
        stage_half(); stage_half();
        u16x8 bf[24]; preload(bf);
#pragma unroll
        for (int kf=0; kf<24; ++kf)
          aZ = mfma32(hold[kf], bf[kf], aZ);
        phase_end();
      }
      { // phase c*4+3: gh_n + GRU elementwise, blended in place in hn slice
        stage_half(); stage_half();
        u16x8 bf[24]; preload(bf);
#pragma unroll
        for (int kf=0; kf<24; ++kf)
          aNH = mfma32(hold[kf], bf[kf], aNH);
#pragma unroll
        for (int r=0;r<16;++r){
          int row = (r&3) + ((r>>2)<<3) + 4*hl;
          float rr = sigf(aR[r]);
          float zz = sigf(aZ[r]);
          float nn = tanh_(aNI[r] + rr*aNH[r]);
          int off = row*HS + c*32 + m;
          float ho = b2f(hw[off]);             // old h
          hw[off] = f2b((1.f-zz)*nn + zz*ho);  // new h, in place
        }
        phase_end();
      }
    } // chunks

    // ---- reload hold[] from hn (full new h for this wave's 32 rows)
    lds_fence();
#pragma unroll
    for (int kf=0; kf<24; ++kf)
      hold[kf] = *(const u16x8*)&hw[m*HS + kf*16 + hl*8];

    // ---- decode: d1 = elu(h@Wd1^T + bd1) [2 tiles], then d2 via padded-N MFMA
    f32x16 a0, a1;
#pragma unroll
    for (int r=0;r<16;++r){ a0[r]=bd1v0; a1[r]=bd1v1; }
    { // phase 48: Wd1 tile 0
      stage_half(); stage_half();
      u16x8 bf[24]; preload(bf);
#pragma unroll
      for (int kf=0; kf<24; ++kf)
        a0 = mfma32(hold[kf], bf[kf], a0);
      phase_end();
    }
    { // phase 49: Wd1 tile 1 (+ epilogue); staging wraps into next t's stream
      stage_half(); stage_half();
      u16x8 bf[24]; preload(bf);
#pragma unroll
      for (int kf=0; kf<24; ++kf)
        a1 = mfma32(hold[kf], bf[kf], a1);

      // Wd2 frags (short live range, L1-hot)
      u16x8 wd2f0 = *(const u16x8*)(wd2p + 0*512 + lane*8);
      u16x8 wd2f1 = *(const u16x8*)(wd2p + 1*512 + lane*8);
      u16x8 wd2f2 = *(const u16x8*)(wd2p + 2*512 + lane*8);
      u16x8 wd2f3 = *(const u16x8*)(wd2p + 3*512 + lane*8);

      f32x16 ao;
#pragma unroll
      for (int r=0;r<16;++r) ao[r]=0.f;
      // pass 0: d1 units 0..31 (hn chunk-0 slice as scratch)
#pragma unroll
      for (int r=0;r<16;++r){
        int row = (r&3) + ((r>>2)<<3) + 4*hl;
        float e = a0[r]; e = e>0.f ? e : (__expf(e)-1.f);
        hw[row*HS + m] = f2b(e);
      }
      lds_fence();
      {
        u16x8 af0 = *(const u16x8*)&hw[m*HS + hl*8];
        u16x8 af1 = *(const u16x8*)&hw[m*HS + 16 + hl*8];
        ao = mfma32(af0, wd2f0, ao);
        ao = mfma32(af1, wd2f1, ao);
      }
      lds_fence();
      // pass 1: d1 units 32..63
#pragma unroll
      for (int r=0;r<16;++r){
        int row = (r&3) + ((r>>2)<<3) + 4*hl;
        float e = a1[r]; e = e>0.f ? e : (__expf(e)-1.f);
        hw[row*HS + m] = f2b(e);
      }
      lds_fence();
      {
        u16x8 af0 = *(const u16x8*)&hw[m*HS + hl*8];
        u16x8 af1 = *(const u16x8*)&hw[m*HS + 16 + hl*8];
        ao = mfma32(af0, wd2f2, ao);
        ao = mfma32(af1, wd2f3, ao);
      }
      lds_fence();
      // restore chunk-0 slice of NEW h from hold (CONSTANT indices)
      *(u16x8*)&hw[m*HS + hl*8]      = hold[0];
      *(u16x8*)&hw[m*HS + 16 + hl*8] = hold[1];

      // out + state update (C cols 0..2 valid); sst in hn padding
#pragma unroll
      for (int r=0;r<16;++r){
        int row = (r&3) + ((r>>2)<<3) + 4*hl;
        if (m < 3){
          float* q = (float*)&hw[row*HS + 384];
          float ns = q[m] + ao[r] + bd2v;
          out[(size_t)(R0+row)*(TT*3) + t*3 + m] = ns;
          q[m] = ns;
        }
      }
      phase_end();
    }
  } // t
}

// -------------------------------------------------------------- launch ----
extern "C" void kernel_launch(void* const* d_in, const int* in_sizes, int n_in,
                              void* d_out, int out_size, void* d_ws, size_t ws_size,
                              hipStream_t stream)
{
  (void)in_sizes; (void)n_in; (void)out_size; (void)ws_size;
  const float* ih     = (const float*)d_in[0];
  const float* plan   = (const float*)d_in[1];
  const float* gatep  = (const float*)d_in[2];
  const float* istate = (const float*)d_in[3];
  const float* Wp     = (const float*)d_in[4];
  const float* bp     = (const float*)d_in[5];
  const float* Ws     = (const float*)d_in[6];
  const float* bs     = (const float*)d_in[7];
  const float* Wih    = (const float*)d_in[8];
  const float* bih    = (const float*)d_in[9];
  const float* Whh    = (const float*)d_in[10];
  const float* bhh    = (const float*)d_in[11];
  const float* Wd1    = (const float*)d_in[12];
  const float* bd1    = (const float*)d_in[13];
  const float* Wd2    = (const float*)d_in[14];
  const float* bd2    = (const float*)d_in[15];

  // workspace layout (~1.25 MB)
  u16*   wstream = (u16*)d_ws;                         // 614400 u16 = 1228800 B
  u16*   wd2p    = (u16*)((char*)d_ws + 1228800);      //   2048 u16 =    4096 B
  u16*   wxp     = (u16*)((char*)d_ws + 1232896);      //   2048 u16 =    4096 B
  float* gb      = (float*)((char*)d_ws + 1236992);    //   1536 f32 =    6144 B

  prep_kernel<<<1728, 256, 0, stream>>>(Wih, Whh, Wd1, Wd2, bih, bhh, Ws, bs, Wp, bp,
                                        wstream, wd2p, wxp, gb);
  gru_main<<<256, 256, 0, stream>>>(ih, plan, gatep, istate,
                                    wstream, wd2p, wxp, gb, bd1, bd2, (float*)d_out);
}